// Round 1
// baseline (300.601 us; speedup 1.0000x reference)
//
#include <hip/hip_runtime.h>
#include <math.h>

#define NB 64
#define LIN 4001
#define LC 998
#define ND 1000
#define EPSBN 1e-5f

// ws layout (float offsets)
#define OFF_CONV 0u        // 3*64*998   = 191616
#define OFF_P    191616u   // 12*64*1000 = 768000
#define OFF_Q    959616u   // 64*1000    = 64000
#define OFF_KV   1023616u  // 64*2048    = 131072
#define OFF_CF   1154688u  // 64*1000    = 64000

// ---------------- K1: fused BatchNorm + strided conv (q,k,v share window) ----
__global__ __launch_bounds__(256) void k_bnconv(
    const float* __restrict__ x,
    const float* __restrict__ g, const float* __restrict__ be,
    const float* __restrict__ mu, const float* __restrict__ va,
    const float* __restrict__ cwq, const float* __restrict__ cbq,
    const float* __restrict__ cwk, const float* __restrict__ cbk,
    const float* __restrict__ cwv, const float* __restrict__ cbv,
    float* __restrict__ conv)
{
    int j = blockIdx.x * 256 + threadIdx.x;
    int b = blockIdx.y;
    if (j >= LC) return;
    const float* xb = x + (size_t)b * LIN + 4 * j;
    float aq = 0.f, ak = 0.f, av = 0.f;
#pragma unroll
    for (int t = 0; t < 10; ++t) {
        int i = 4 * j + t;
        float s  = g[i] * rsqrtf(va[i] + EPSBN);
        float xn = (xb[t] - mu[i]) * s + be[i];
        aq = fmaf(xn, cwq[t], aq);
        ak = fmaf(xn, cwk[t], ak);
        av = fmaf(xn, cwv[t], av);
    }
    conv[(size_t)(0 * NB + b) * LC + j] = aq + cbq[0];
    conv[(size_t)(1 * NB + b) * LC + j] = ak + cbk[0];
    conv[(size_t)(2 * NB + b) * LC + j] = av + cbv[0];
}

// ---------------- K2: QKV linear GEMM (64x998)@(998x1000)^T x3, j-split x4 ---
// lanes = 64 d-columns (lw chunk in LDS, stride 65 -> conflict-free);
// conv rows are wave-uniform -> scalar loads. Partial sums to P.
__global__ __launch_bounds__(256) void k_lin(
    const float* __restrict__ conv,
    const float* __restrict__ lwq, const float* __restrict__ lwk,
    const float* __restrict__ lwv,
    float* __restrict__ P)
{
    __shared__ float lds[250 * 65];
    int tid  = threadIdx.x;
    int lane = tid & 63;
    int wg   = __builtin_amdgcn_readfirstlane(tid >> 6);
    int d0    = blockIdx.x * 64;
    int which = blockIdx.y;
    int chunk = blockIdx.z;
    int j0 = chunk * 250;
    int jc = (LC - j0 < 250) ? (LC - j0) : 250;
    const float* lw = (which == 0) ? lwq : ((which == 1) ? lwk : lwv);
#pragma unroll 4
    for (int rr = 0; rr < 64; ++rr) {
        int dd = d0 + rr;
        if (tid < jc)
            lds[tid * 65 + rr] = (dd < ND) ? lw[(size_t)dd * LC + j0 + tid] : 0.f;
    }
    __syncthreads();
    float acc[16];
#pragma unroll
    for (int bb = 0; bb < 16; ++bb) acc[bb] = 0.f;
    const float* cb = conv + ((size_t)which * NB + wg * 16) * LC + j0;
    for (int jj = 0; jj < jc; ++jj) {
        float w = lds[jj * 65 + lane];
#pragma unroll
        for (int bb = 0; bb < 16; ++bb)
            acc[bb] = fmaf(cb[(size_t)bb * LC + jj], w, acc[bb]);
    }
    int d = d0 + lane;
    if (d < ND) {
#pragma unroll
        for (int bb = 0; bb < 16; ++bb)
            P[((size_t)(chunk * 3 + which) * NB + wg * 16 + bb) * ND + d] = acc[bb];
    }
}

// ---------------- K3: combine partials + bias + ReLU + in_proj --------------
__global__ __launch_bounds__(256) void k_act(
    const float* __restrict__ P,
    const float* __restrict__ lbq, const float* __restrict__ lbk,
    const float* __restrict__ lbv,
    const float* __restrict__ ipw, const float* __restrict__ ipb,
    float* __restrict__ q, float* __restrict__ kv)
{
    int i = blockIdx.x * 256 + threadIdx.x;
    int b = blockIdx.y;
    if (i >= ND) return;
    float s0 = 0.f, s1 = 0.f, s2 = 0.f;
#pragma unroll
    for (int c = 0; c < 4; ++c) {
        s0 += P[((size_t)(c * 3 + 0) * NB + b) * ND + i];
        s1 += P[((size_t)(c * 3 + 1) * NB + b) * ND + i];
        s2 += P[((size_t)(c * 3 + 2) * NB + b) * ND + i];
    }
    float yq = fmaxf(s0 + lbq[i], 0.f) * ipw[0] + ipb[0];
    float yk = fmaxf(s1 + lbk[i], 0.f) * ipw[1] + ipb[1];
    float yv = fmaxf(s2 + lbv[i], 0.f) * ipw[2] + ipb[2];
    q[(size_t)b * ND + i] = yq;
    kv[(size_t)b * 2048 + 2 * i]     = yk;
    kv[(size_t)b * 2048 + 2 * i + 1] = yv;
}

// ---------------- K4: attention: softmax_j(q_i*k_j) . v, + out_proj affine --
// scores never materialized. k/v streamed via wave-uniform scalar loads.
// per-row max is q_i*kmax (q_i>=0) or q_i*kmin -> no overflow.
__global__ __launch_bounds__(256) void k_attn(
    const float* __restrict__ q, const float* __restrict__ kv,
    const float* __restrict__ opw, const float* __restrict__ opb,
    float* __restrict__ cf)
{
    __shared__ float sred[512];
    __shared__ float rmax[4];
    __shared__ float rmin[4];
    int tid  = threadIdx.x;
    int b    = blockIdx.y;
    int half = tid >> 7;           // wave-uniform (waves 0,1 -> 0; 2,3 -> 1)
    int ii   = tid & 127;
    int i    = blockIdx.x * 128 + ii;

    // block-wide kmax/kmin over k[b][:]
    const float2* kv2 = (const float2*)(kv + (size_t)b * 2048);
    float km = -INFINITY, kn = INFINITY;
    for (int idx = tid; idx < ND; idx += 256) {
        float2 f = kv2[idx];
        km = fmaxf(km, f.x);
        kn = fminf(kn, f.x);
    }
#pragma unroll
    for (int off = 1; off < 64; off <<= 1) {
        km = fmaxf(km, __shfl_xor(km, off));
        kn = fminf(kn, __shfl_xor(kn, off));
    }
    if ((tid & 63) == 0) { rmax[tid >> 6] = km; rmin[tid >> 6] = kn; }
    __syncthreads();
    km = fmaxf(fmaxf(rmax[0], rmax[1]), fmaxf(rmax[2], rmax[3]));
    kn = fminf(fminf(rmin[0], rmin[1]), fminf(rmin[2], rmin[3]));

    float qi = (i < ND) ? q[(size_t)b * ND + i] : 0.f;
    float m  = (qi >= 0.f) ? qi * km : qi * kn;

    const float* kvb = kv + (size_t)b * 2048
                     + (size_t)__builtin_amdgcn_readfirstlane(half) * 1000;
    float den = 0.f, num = 0.f;
#pragma unroll 4
    for (int jl = 0; jl < 500; ++jl) {
        float kj = kvb[2 * jl];
        float vj = kvb[2 * jl + 1];
        float e  = __expf(fmaf(qi, kj, -m));
        den += e;
        num = fmaf(e, vj, num);
    }
    sred[tid]       = den;
    sred[256 + tid] = num;
    __syncthreads();
    if (half == 0 && i < ND) {
        float dt  = sred[ii] + sred[128 + ii];
        float nt  = sred[256 + ii] + sred[256 + 128 + ii];
        float ctx = nt / dt;
        cf[(size_t)b * ND + i] = ctx * opw[0] + opb[0];
    }
}

// ---------------- K5: out GEMM (64x1000)@(1000x1000)^T, e-split x8, atomic ---
__global__ __launch_bounds__(256) void k_out(
    const float* __restrict__ cf, const float* __restrict__ W,
    const float* __restrict__ outb, float* __restrict__ out)
{
    __shared__ float lds[125 * 65];
    int tid  = threadIdx.x;
    int lane = tid & 63;
    int wg   = __builtin_amdgcn_readfirstlane(tid >> 6);
    int d0 = blockIdx.x * 64;
    int e0 = blockIdx.y * 125;
#pragma unroll 4
    for (int rr = 0; rr < 64; ++rr) {
        int dd = d0 + rr;
        if (tid < 125)
            lds[tid * 65 + rr] = (dd < ND) ? W[(size_t)dd * ND + e0 + tid] : 0.f;
    }
    __syncthreads();
    float acc[16];
#pragma unroll
    for (int bb = 0; bb < 16; ++bb) acc[bb] = 0.f;
    const float* cb = cf + (size_t)(wg * 16) * ND + e0;
    for (int jj = 0; jj < 125; ++jj) {
        float w = lds[jj * 65 + lane];
#pragma unroll
        for (int bb = 0; bb < 16; ++bb)
            acc[bb] = fmaf(cb[(size_t)bb * ND + jj], w, acc[bb]);
    }
    int d = d0 + lane;
    if (d < ND) {
        float bias = (blockIdx.y == 0) ? outb[d] : 0.f;
#pragma unroll
        for (int bb = 0; bb < 16; ++bb)
            atomicAdd(out + (size_t)(wg * 16 + bb) * ND + d, acc[bb] + bias);
    }
}

extern "C" void kernel_launch(void* const* d_in, const int* in_sizes, int n_in,
                              void* d_out, int out_size, void* d_ws, size_t ws_size,
                              hipStream_t stream)
{
    const float* x    = (const float*)d_in[0];
    const float* g    = (const float*)d_in[1];
    const float* be   = (const float*)d_in[2];
    const float* mu   = (const float*)d_in[3];
    const float* va   = (const float*)d_in[4];
    const float* cwq  = (const float*)d_in[5];
    const float* cbq  = (const float*)d_in[6];
    const float* lwq  = (const float*)d_in[7];
    const float* lbq  = (const float*)d_in[8];
    const float* cwk  = (const float*)d_in[9];
    const float* cbk  = (const float*)d_in[10];
    const float* lwk  = (const float*)d_in[11];
    const float* lbk  = (const float*)d_in[12];
    const float* cwv  = (const float*)d_in[13];
    const float* cbv  = (const float*)d_in[14];
    const float* lwv  = (const float*)d_in[15];
    const float* lbv  = (const float*)d_in[16];
    const float* ipw  = (const float*)d_in[17];
    const float* ipb  = (const float*)d_in[18];
    const float* opw  = (const float*)d_in[19];
    const float* opb  = (const float*)d_in[20];
    const float* W    = (const float*)d_in[21];
    const float* outb = (const float*)d_in[22];

    float* ws   = (float*)d_ws;
    float* conv = ws + OFF_CONV;
    float* P    = ws + OFF_P;
    float* q    = ws + OFF_Q;
    float* kv   = ws + OFF_KV;
    float* cf   = ws + OFF_CF;
    float* out  = (float*)d_out;

    hipMemsetAsync(d_out, 0, (size_t)out_size * sizeof(float), stream);

    k_bnconv<<<dim3(4, 64), 256, 0, stream>>>(x, g, be, mu, va,
                                              cwq, cbq, cwk, cbk, cwv, cbv, conv);
    k_lin  <<<dim3(16, 3, 4), 256, 0, stream>>>(conv, lwq, lwk, lwv, P);
    k_act  <<<dim3(4, 64), 256, 0, stream>>>(P, lbq, lbk, lbv, ipw, ipb, q, kv);
    k_attn <<<dim3(8, 64), 256, 0, stream>>>(q, kv, opw, opb, cf);
    k_out  <<<dim3(16, 8), 256, 0, stream>>>(cf, W, outb, out);
}

// Round 2
// 197.111 us; speedup vs baseline: 1.5250x; 1.5250x over previous
//
#include <hip/hip_runtime.h>
#include <math.h>

#define NB 64
#define LIN 4001
#define LC 998
#define ND 1000
#define EPSBN 1e-5f

// ws layout (float offsets)
#define OFF_CONVT 0u        // 3*998*64  = 191616
#define OFF_P     191616u   // 3*16*4096 = 196608
#define OFF_Q     388224u   // 64*1000   = 64000
#define OFF_KV    452224u   // 64*2048   = 131072
#define OFF_CF    583296u   // 1000*64   = 64000  (cfT[i][b])
// total 647296 floats = 2.59 MB

// ---------------- K1: fused BatchNorm + strided conv, writes convT[w][j][b] --
__global__ __launch_bounds__(256) void k_bnconv(
    const float* __restrict__ x,
    const float* __restrict__ g, const float* __restrict__ be,
    const float* __restrict__ mu, const float* __restrict__ va,
    const float* __restrict__ cwq, const float* __restrict__ cbq,
    const float* __restrict__ cwk, const float* __restrict__ cbk,
    const float* __restrict__ cwv, const float* __restrict__ cbv,
    float* __restrict__ convT)
{
    int j = blockIdx.x * 256 + threadIdx.x;
    int b = blockIdx.y;
    if (j >= LC) return;
    const float* xb = x + (size_t)b * LIN + 4 * j;
    float aq = 0.f, ak = 0.f, av = 0.f;
#pragma unroll
    for (int t = 0; t < 10; ++t) {
        int i = 4 * j + t;
        float s  = g[i] * rsqrtf(va[i] + EPSBN);
        float xn = (xb[t] - mu[i]) * s + be[i];
        aq = fmaf(xn, cwq[t], aq);
        ak = fmaf(xn, cwk[t], ak);
        av = fmaf(xn, cwv[t], av);
    }
    convT[((size_t)0 * LC + j) * 64 + b] = aq + cbq[0];
    convT[((size_t)1 * LC + j) * 64 + b] = ak + cbk[0];
    convT[((size_t)2 * LC + j) * 64 + b] = av + cbv[0];
}

// ---------------- K2: QKV GEMM, 8x8 microtile, LDS-staged, atomic P accum ----
// grid (16 d-tiles, 3 which, 8 k-chunks of 125). block 256 = 4 waves.
// waves split the 125-k chunk; 4-buffer LDS reduce; atomicAdd into P.
__global__ __launch_bounds__(256) void k_lin(
    const float* __restrict__ convT,
    const float* __restrict__ lwq, const float* __restrict__ lwk,
    const float* __restrict__ lwv,
    float* __restrict__ P)
{
    __shared__ float lds[16384];           // 64 KB
    float* ldsC = lds;                     // [jc][64]   up to 8000 floats
    float* ldsW = lds + 8000;              // [64][127]  = 8128 floats
    int tid  = threadIdx.x;
    int lane = tid & 63;
    int w    = tid >> 6;
    int b0   = (lane & 7) << 3;
    int d0   = (lane >> 3) << 3;
    int dgb   = blockIdx.x * 64;
    int which = blockIdx.y;
    int chunk = blockIdx.z;
    int j0 = chunk * 125;
    int jc = (LC - j0 < 125) ? (LC - j0) : 125;   // 125 (last: 123)
    const float* lw = (which == 0) ? lwq : ((which == 1) ? lwk : lwv);

    // stage convT chunk (contiguous) via float4
    {
        const float4* src = (const float4*)(convT + ((size_t)which * LC + j0) * 64);
        float4* dst = (float4*)ldsC;
        for (int t = tid; t < jc * 16; t += 256) dst[t] = src[t];
    }
    // stage weight tile [64 d][jc], coalesced along j, stride-127 pad
    for (int idx = tid; idx < 8192; idx += 256) {
        int dd = idx >> 7, jj = idx & 127;
        if (jj < 127) {
            int dg = dgb + dd;
            ldsW[dd * 127 + jj] =
                (dg < ND && jj < jc) ? lw[(size_t)dg * LC + j0 + jj] : 0.f;
        }
    }
    __syncthreads();

    float acc[8][8];
#pragma unroll
    for (int i = 0; i < 8; ++i)
#pragma unroll
        for (int jx = 0; jx < 8; ++jx) acc[i][jx] = 0.f;

    int js = w * 32;
    int je = (jc < js + 32) ? jc : (js + 32);
    for (int jj = js; jj < je; ++jj) {
        float4 c0 = *(const float4*)(ldsC + jj * 64 + b0);
        float4 c1 = *(const float4*)(ldsC + jj * 64 + b0 + 4);
        float cv[8] = {c0.x, c0.y, c0.z, c0.w, c1.x, c1.y, c1.z, c1.w};
        float wv[8];
#pragma unroll
        for (int r = 0; r < 8; ++r) wv[r] = ldsW[(d0 + r) * 127 + jj];
#pragma unroll
        for (int i = 0; i < 8; ++i)
#pragma unroll
            for (int jx = 0; jx < 8; ++jx)
                acc[i][jx] = fmaf(cv[i], wv[jx], acc[i][jx]);
    }

    __syncthreads();                       // done reading staged data
    // phase A: each wave -> its own 16 KB buffer (parallel)
    float* red = lds + w * 4096;
#pragma unroll
    for (int i = 0; i < 8; ++i) {
        *(float4*)(red + (b0 + i) * 64 + d0) =
            make_float4(acc[i][0], acc[i][1], acc[i][2], acc[i][3]);
        *(float4*)(red + (b0 + i) * 64 + d0 + 4) =
            make_float4(acc[i][4], acc[i][5], acc[i][6], acc[i][7]);
    }
    __syncthreads();
    // phase B: sum 4 buffers, atomicAdd into P tile
    float* Pt = P + ((size_t)(which * 16 + blockIdx.x)) * 4096;
    for (int t = tid; t < 1024; t += 256) {
        float4 a = ((const float4*)lds)[t];
        float4 bq = ((const float4*)(lds + 4096))[t];
        float4 c = ((const float4*)(lds + 8192))[t];
        float4 d = ((const float4*)(lds + 12288))[t];
        atomicAdd(Pt + t * 4 + 0, a.x + bq.x + c.x + d.x);
        atomicAdd(Pt + t * 4 + 1, a.y + bq.y + c.y + d.y);
        atomicAdd(Pt + t * 4 + 2, a.z + bq.z + c.z + d.z);
        atomicAdd(Pt + t * 4 + 3, a.w + bq.w + c.w + d.w);
    }
}

// ---------------- K3: bias + ReLU + in_proj -> q, kv ------------------------
__global__ __launch_bounds__(256) void k_act(
    const float* __restrict__ P,
    const float* __restrict__ lbq, const float* __restrict__ lbk,
    const float* __restrict__ lbv,
    const float* __restrict__ ipw, const float* __restrict__ ipb,
    float* __restrict__ q, float* __restrict__ kv)
{
    int i = blockIdx.x * 256 + threadIdx.x;
    int b = blockIdx.y;
    if (i >= ND) return;
    int it = i >> 6, il = i & 63;
    size_t cell = (size_t)it * 4096 + (b << 6) + il;
    float s0 = P[(0 * 16) * 4096 + cell];
    float s1 = P[(1 * 16) * 4096 + cell];
    float s2 = P[(2 * 16) * 4096 + cell];
    float yq = fmaxf(s0 + lbq[i], 0.f) * ipw[0] + ipb[0];
    float yk = fmaxf(s1 + lbk[i], 0.f) * ipw[1] + ipb[1];
    float yv = fmaxf(s2 + lbv[i], 0.f) * ipw[2] + ipb[2];
    q[(size_t)b * ND + i] = yq;
    kv[(size_t)b * 2048 + 2 * i]     = yk;
    kv[(size_t)b * 2048 + 2 * i + 1] = yv;
}

// ---------------- K4: attention (LDS-staged k/v, broadcast reads) -----------
// grid (8 i-tiles of 128, 64 b). writes cfT[i][b] (transposed, + out_proj).
__global__ __launch_bounds__(256) void k_attn(
    const float* __restrict__ q, const float* __restrict__ kv,
    const float* __restrict__ opw, const float* __restrict__ opb,
    float* __restrict__ cfT)
{
    __shared__ float ldsKV[2048];
    __shared__ float sred[512];
    __shared__ float rmax[4];
    __shared__ float rmin[4];
    int tid  = threadIdx.x;
    int b    = blockIdx.y;
    int half = tid >> 7;
    int ii   = tid & 127;
    int i    = blockIdx.x * 128 + ii;

    {   // stage kv[b] (8 KB)
        const float4* src = (const float4*)(kv + (size_t)b * 2048);
        float4* dst = (float4*)ldsKV;
        for (int t = tid; t < 512; t += 256) dst[t] = src[t];
    }
    __syncthreads();

    // block-wide kmax/kmin
    float km = -INFINITY, kn = INFINITY;
    const float2* kv2 = (const float2*)ldsKV;
    for (int idx = tid; idx < ND; idx += 256) {
        float2 f = kv2[idx];
        km = fmaxf(km, f.x);
        kn = fminf(kn, f.x);
    }
#pragma unroll
    for (int off = 1; off < 64; off <<= 1) {
        km = fmaxf(km, __shfl_xor(km, off));
        kn = fminf(kn, __shfl_xor(kn, off));
    }
    if ((tid & 63) == 0) { rmax[tid >> 6] = km; rmin[tid >> 6] = kn; }
    __syncthreads();
    km = fmaxf(fmaxf(rmax[0], rmax[1]), fmaxf(rmax[2], rmax[3]));
    kn = fminf(fminf(rmin[0], rmin[1]), fminf(rmin[2], rmin[3]));

    float qi = (i < ND) ? q[(size_t)b * ND + i] : 0.f;
    float m  = (qi >= 0.f) ? qi * km : qi * kn;

    int jbase = half * 500;
    float den = 0.f, num = 0.f;
#pragma unroll 4
    for (int jl = 0; jl < 500; ++jl) {
        float2 f = kv2[jbase + jl];
        float e  = __expf(fmaf(qi, f.x, -m));
        den += e;
        num = fmaf(e, f.y, num);
    }
    sred[tid]       = den;
    sred[256 + tid] = num;
    __syncthreads();
    if (half == 0 && i < ND) {
        float dt  = sred[ii] + sred[128 + ii];
        float nt  = sred[256 + ii] + sred[256 + 128 + ii];
        float ctx = nt / dt;
        cfT[(size_t)i * 64 + b] = ctx * opw[0] + opb[0];
    }
}

// ---------------- K5: out GEMM, 8x8 microtile, atomicAdd into out -----------
// grid (16 e-tiles, 8 k-chunks of 125). A = cfT[i][b], B = W[e][i].
__global__ __launch_bounds__(256) void k_out(
    const float* __restrict__ cfT, const float* __restrict__ W,
    const float* __restrict__ outb, float* __restrict__ out)
{
    __shared__ float lds[16384];
    float* ldsC = lds;
    float* ldsW = lds + 8000;
    int tid  = threadIdx.x;
    int lane = tid & 63;
    int w    = tid >> 6;
    int b0   = (lane & 7) << 3;
    int d0   = (lane >> 3) << 3;
    int egb   = blockIdx.x * 64;
    int chunk = blockIdx.y;
    int j0 = chunk * 125;                  // K = 1000 = 8*125 exactly

    {
        const float4* src = (const float4*)(cfT + (size_t)j0 * 64);
        float4* dst = (float4*)ldsC;
        for (int t = tid; t < 125 * 16; t += 256) dst[t] = src[t];
    }
    for (int idx = tid; idx < 8192; idx += 256) {
        int dd = idx >> 7, jj = idx & 127;
        if (jj < 127) {
            int eg = egb + dd;
            ldsW[dd * 127 + jj] =
                (eg < ND && jj < 125) ? W[(size_t)eg * ND + j0 + jj] : 0.f;
        }
    }
    __syncthreads();

    float acc[8][8];
#pragma unroll
    for (int i = 0; i < 8; ++i)
#pragma unroll
        for (int jx = 0; jx < 8; ++jx) acc[i][jx] = 0.f;

    int js = w * 32;
    int je = (125 < js + 32) ? 125 : (js + 32);
    for (int jj = js; jj < je; ++jj) {
        float4 c0 = *(const float4*)(ldsC + jj * 64 + b0);
        float4 c1 = *(const float4*)(ldsC + jj * 64 + b0 + 4);
        float cv[8] = {c0.x, c0.y, c0.z, c0.w, c1.x, c1.y, c1.z, c1.w};
        float wv[8];
#pragma unroll
        for (int r = 0; r < 8; ++r) wv[r] = ldsW[(d0 + r) * 127 + jj];
#pragma unroll
        for (int i = 0; i < 8; ++i)
#pragma unroll
            for (int jx = 0; jx < 8; ++jx)
                acc[i][jx] = fmaf(cv[i], wv[jx], acc[i][jx]);
    }

    __syncthreads();
    float* red = lds + w * 4096;
#pragma unroll
    for (int i = 0; i < 8; ++i) {
        *(float4*)(red + (b0 + i) * 64 + d0) =
            make_float4(acc[i][0], acc[i][1], acc[i][2], acc[i][3]);
        *(float4*)(red + (b0 + i) * 64 + d0 + 4) =
            make_float4(acc[i][4], acc[i][5], acc[i][6], acc[i][7]);
    }
    __syncthreads();
    for (int t = tid; t < 4096; t += 256) {
        int bb = t >> 6, dd = t & 63;
        int eg = egb + dd;
        if (eg < ND) {
            float v = lds[t] + lds[4096 + t] + lds[8192 + t] + lds[12288 + t];
            if (chunk == 0) v += outb[eg];
            atomicAdd(out + (size_t)bb * ND + eg, v);
        }
    }
}

extern "C" void kernel_launch(void* const* d_in, const int* in_sizes, int n_in,
                              void* d_out, int out_size, void* d_ws, size_t ws_size,
                              hipStream_t stream)
{
    const float* x    = (const float*)d_in[0];
    const float* g    = (const float*)d_in[1];
    const float* be   = (const float*)d_in[2];
    const float* mu   = (const float*)d_in[3];
    const float* va   = (const float*)d_in[4];
    const float* cwq  = (const float*)d_in[5];
    const float* cbq  = (const float*)d_in[6];
    const float* lwq  = (const float*)d_in[7];
    const float* lbq  = (const float*)d_in[8];
    const float* cwk  = (const float*)d_in[9];
    const float* cbk  = (const float*)d_in[10];
    const float* lwk  = (const float*)d_in[11];
    const float* lbk  = (const float*)d_in[12];
    const float* cwv  = (const float*)d_in[13];
    const float* cbv  = (const float*)d_in[14];
    const float* lwv  = (const float*)d_in[15];
    const float* lbv  = (const float*)d_in[16];
    const float* ipw  = (const float*)d_in[17];
    const float* ipb  = (const float*)d_in[18];
    const float* opw  = (const float*)d_in[19];
    const float* opb  = (const float*)d_in[20];
    const float* W    = (const float*)d_in[21];
    const float* outb = (const float*)d_in[22];

    float* ws    = (float*)d_ws;
    float* convT = ws + OFF_CONVT;
    float* P     = ws + OFF_P;
    float* q     = ws + OFF_Q;
    float* kv    = ws + OFF_KV;
    float* cfT   = ws + OFF_CF;
    float* out   = (float*)d_out;

    hipMemsetAsync(P, 0, 196608u * sizeof(float), stream);
    hipMemsetAsync(d_out, 0, (size_t)out_size * sizeof(float), stream);

    k_bnconv<<<dim3(4, 64), 256, 0, stream>>>(x, g, be, mu, va,
                                              cwq, cbq, cwk, cbk, cwv, cbv, convT);
    k_lin  <<<dim3(16, 3, 8), 256, 0, stream>>>(convT, lwq, lwk, lwv, P);
    k_act  <<<dim3(4, 64), 256, 0, stream>>>(P, lbq, lbk, lbv, ipw, ipb, q, kv);
    k_attn <<<dim3(8, 64), 256, 0, stream>>>(q, kv, opw, opb, cfT);
    k_out  <<<dim3(16, 8), 256, 0, stream>>>(cfT, W, outb, out);
}

// Round 3
// 166.309 us; speedup vs baseline: 1.8075x; 1.1852x over previous
//
#include <hip/hip_runtime.h>
#include <math.h>

#define NB 64
#define LIN 4001
#define LC 998
#define ND 1000
#define EPSBN 1e-5f

#define CK 96            // K-chunk for k_lin & k_out
#define NCH_LIN 11       // ceil(998/96)
#define NCH_OUT 11       // ceil(1000/96)

// ws float offsets
#define OFF_CONVT 0u        // 3*998*64      = 191616
#define OFF_PP    191616u   // 11*3*16*4096  = 2162688
#define OFF_Q     2354304u  // 64*1000       = 64000
#define OFF_KV    2418304u  // 64*2048       = 131072
#define OFF_CF    2549376u  // 1000*64       = 64000   (cfT[i][b])
#define OFF_OP    2613376u  // 11*16*4096    = 720896
// end = 3334272 floats = 13.3 MB

// ---------------- K1: fused BatchNorm + strided conv -> convT[w][j][b] ------
__global__ __launch_bounds__(256) void k_bnconv(
    const float* __restrict__ x,
    const float* __restrict__ g, const float* __restrict__ be,
    const float* __restrict__ mu, const float* __restrict__ va,
    const float* __restrict__ cwq, const float* __restrict__ cbq,
    const float* __restrict__ cwk, const float* __restrict__ cbk,
    const float* __restrict__ cwv, const float* __restrict__ cbv,
    float* __restrict__ convT)
{
    int j = blockIdx.x * 256 + threadIdx.x;
    int b = blockIdx.y;
    if (j >= LC) return;
    const float* xb = x + (size_t)b * LIN + 4 * j;
    float aq = 0.f, ak = 0.f, av = 0.f;
#pragma unroll
    for (int t = 0; t < 10; ++t) {
        int i = 4 * j + t;
        float s  = g[i] * rsqrtf(va[i] + EPSBN);
        float xn = (xb[t] - mu[i]) * s + be[i];
        aq = fmaf(xn, cwq[t], aq);
        ak = fmaf(xn, cwk[t], ak);
        av = fmaf(xn, cwv[t], av);
    }
    convT[((size_t)0 * LC + j) * 64 + b] = aq + cbq[0];
    convT[((size_t)1 * LC + j) * 64 + b] = ak + cbk[0];
    convT[((size_t)2 * LC + j) * 64 + b] = av + cbv[0];
}

// ---------------- shared GEMM microtile body (64b x 64d x CK), no atomics ---
// grid z/y pick chunk & matrix. Waves split K; two-pass compact-f4 LDS reduce.
__device__ __forceinline__ void gemm_tile(
    const float* __restrict__ Asrc,   // [jc][64] chunk, b-contiguous
    const float* __restrict__ Brow,   // weight base, row stride ldB
    int ldB, int dgb, int j0, int jc,
    float* __restrict__ Pt,           // output tile [64 b][64 d]
    float* lds)
{
    float* ldsC = lds;                // [96][64]  = 6144
    float* ldsW = lds + 6144;         // [64][97]  = 6208
    int tid  = threadIdx.x;
    int lane = tid & 63;
    int w    = tid >> 6;
    int b0   = (lane & 7) << 3;
    int d0   = (lane >> 3) << 3;

    {   // stage A chunk via float4 (fully coalesced)
        const float4* src = (const float4*)Asrc;
        float4* dst = (float4*)ldsC;
        for (int t = tid; t < jc * 16; t += 256) dst[t] = src[t];
    }
    // stage B tile via float2 (row starts & j0 are even): 64 rows x 48 f2
    for (int idx = tid; idx < 3072; idx += 256) {
        int dd = idx / 48, j2 = idx % 48;
        int dg = dgb + dd;
        float2 v = make_float2(0.f, 0.f);
        if (dg < ND && 2 * j2 < jc)
            v = *(const float2*)(Brow + (size_t)dg * ldB + j0 + 2 * j2);
        ldsW[dd * 97 + 2 * j2]     = v.x;
        ldsW[dd * 97 + 2 * j2 + 1] = v.y;
    }
    __syncthreads();

    float acc[8][8];
#pragma unroll
    for (int i = 0; i < 8; ++i)
#pragma unroll
        for (int jx = 0; jx < 8; ++jx) acc[i][jx] = 0.f;

    int js = (jc * w) >> 2;
    int je = (jc * (w + 1)) >> 2;
    for (int jj = js; jj < je; ++jj) {
        float4 c0 = *(const float4*)(ldsC + jj * 64 + b0);
        float4 c1 = *(const float4*)(ldsC + jj * 64 + b0 + 4);
        float cv[8] = {c0.x, c0.y, c0.z, c0.w, c1.x, c1.y, c1.z, c1.w};
        float wv[8];
#pragma unroll
        for (int r = 0; r < 8; ++r) wv[r] = ldsW[(d0 + r) * 97 + jj];
#pragma unroll
        for (int i = 0; i < 8; ++i)
#pragma unroll
            for (int jx = 0; jx < 8; ++jx)
                acc[i][jx] = fmaf(cv[i], wv[jx], acc[i][jx]);
    }
    __syncthreads();   // done with staged data; reuse LDS for reduce

    // two passes (f4 halves of each lane's d-range); per-wave buf [64][36]
    for (int p = 0; p < 2; ++p) {
        float* red = lds + w * 2304;
#pragma unroll
        for (int i = 0; i < 8; ++i)
            *(float4*)(red + (b0 + i) * 36 + (d0 >> 1)) =
                make_float4(acc[i][4*p], acc[i][4*p+1], acc[i][4*p+2], acc[i][4*p+3]);
        __syncthreads();
        for (int t = tid; t < 512; t += 256) {
            int bb = t >> 3, gg = t & 7;
            int o = bb * 36 + 4 * gg;
            float4 a0 = *(const float4*)(lds + o);
            float4 a1 = *(const float4*)(lds + 2304 + o);
            float4 a2 = *(const float4*)(lds + 4608 + o);
            float4 a3 = *(const float4*)(lds + 6912 + o);
            float4 s;
            s.x = a0.x + a1.x + a2.x + a3.x;
            s.y = a0.y + a1.y + a2.y + a3.y;
            s.z = a0.z + a1.z + a2.z + a3.z;
            s.w = a0.w + a1.w + a2.w + a3.w;
            *(float4*)(Pt + bb * 64 + 8 * gg + 4 * p) = s;
        }
        __syncthreads();
    }
}

// ---------------- K2: QKV GEMM partials -> Pp (no atomics) ------------------
__global__ __launch_bounds__(256) void k_lin(
    const float* __restrict__ convT,
    const float* __restrict__ lwq, const float* __restrict__ lwk,
    const float* __restrict__ lwv,
    float* __restrict__ Pp)
{
    __shared__ float lds[12352];
    int dgb   = blockIdx.x * 64;
    int which = blockIdx.y;
    int chunk = blockIdx.z;
    int j0 = chunk * CK;
    int jc = (LC - j0 < CK) ? (LC - j0) : CK;
    const float* lw = (which == 0) ? lwq : ((which == 1) ? lwk : lwv);
    const float* Asrc = convT + ((size_t)which * LC + j0) * 64;
    float* Pt = Pp + (((size_t)chunk * 3 + which) * 16 + blockIdx.x) * 4096;
    gemm_tile(Asrc, lw, LC, dgb, j0, jc, Pt, lds);
}

// ---------------- K3: reduce chunks + bias + ReLU + in_proj -> q, kv --------
__global__ __launch_bounds__(256) void k_act(
    const float* __restrict__ Pp,
    const float* __restrict__ lbq, const float* __restrict__ lbk,
    const float* __restrict__ lbv,
    const float* __restrict__ ipw, const float* __restrict__ ipb,
    float* __restrict__ q, float* __restrict__ kv)
{
    int i = blockIdx.x * 256 + threadIdx.x;
    int b = blockIdx.y;
    if (i >= ND) return;
    int it = i >> 6, il = i & 63;
    float s0 = 0.f, s1 = 0.f, s2 = 0.f;
    for (int c = 0; c < NCH_LIN; ++c) {
        size_t base = (((size_t)c * 3) * 16 + it) * 4096 + (il | (b << 6));
        s0 += Pp[base];
        s1 += Pp[base + 16 * 4096];
        s2 += Pp[base + 32 * 4096];
    }
    float yq = fmaxf(s0 + lbq[i], 0.f) * ipw[0] + ipb[0];
    float yk = fmaxf(s1 + lbk[i], 0.f) * ipw[1] + ipb[1];
    float yv = fmaxf(s2 + lbv[i], 0.f) * ipw[2] + ipb[2];
    q[(size_t)b * ND + i] = yq;
    kv[(size_t)b * 2048 + 2 * i]     = yk;
    kv[(size_t)b * 2048 + 2 * i + 1] = yv;
}

// ---------------- K4: attention, 4-way wave K-split, writes cfT[i][b] -------
__global__ __launch_bounds__(256) void k_attn(
    const float* __restrict__ q, const float* __restrict__ kv,
    const float* __restrict__ opw, const float* __restrict__ opb,
    float* __restrict__ cfT)
{
    __shared__ float ldsKV[2048];
    __shared__ float sden[256];
    __shared__ float snum[256];
    __shared__ float rmax[4];
    __shared__ float rmin[4];
    int tid = threadIdx.x;
    int b   = blockIdx.y;
    int w   = tid >> 6;           // wave id (uniform)
    int ii  = tid & 63;
    int i   = blockIdx.x * 64 + ii;

    {   // stage kv[b] (8 KB)
        const float4* src = (const float4*)(kv + (size_t)b * 2048);
        float4* dst = (float4*)ldsKV;
        for (int t = tid; t < 512; t += 256) dst[t] = src[t];
    }
    __syncthreads();

    const float2* kv2 = (const float2*)ldsKV;
    float km = -INFINITY, kn = INFINITY;
    for (int idx = tid; idx < ND; idx += 256) {
        float2 f = kv2[idx];
        km = fmaxf(km, f.x);
        kn = fminf(kn, f.x);
    }
#pragma unroll
    for (int off = 1; off < 64; off <<= 1) {
        km = fmaxf(km, __shfl_xor(km, off));
        kn = fminf(kn, __shfl_xor(kn, off));
    }
    if (ii == 0) { rmax[w] = km; rmin[w] = kn; }
    __syncthreads();
    km = fmaxf(fmaxf(rmax[0], rmax[1]), fmaxf(rmax[2], rmax[3]));
    kn = fminf(fminf(rmin[0], rmin[1]), fminf(rmin[2], rmin[3]));

    float qi = (i < ND) ? q[(size_t)b * ND + i] : 0.f;
    float m  = (qi >= 0.f) ? qi * km : qi * kn;

    int jb = w * 250;
    float den = 0.f, num = 0.f;
#pragma unroll 2
    for (int jl = 0; jl < 250; ++jl) {
        float2 f = kv2[jb + jl];
        float e  = __expf(fmaf(qi, f.x, -m));
        den += e;
        num = fmaf(e, f.y, num);
    }
    sden[tid] = den;
    snum[tid] = num;
    __syncthreads();
    if (w == 0 && i < ND) {
        float dt = sden[ii] + sden[64 + ii] + sden[128 + ii] + sden[192 + ii];
        float nt = snum[ii] + snum[64 + ii] + snum[128 + ii] + snum[192 + ii];
        cfT[(size_t)i * 64 + b] = (nt / dt) * opw[0] + opb[0];
    }
}

// ---------------- K5: out GEMM partials -> Op (no atomics) ------------------
__global__ __launch_bounds__(256) void k_out(
    const float* __restrict__ cfT, const float* __restrict__ W,
    float* __restrict__ Op)
{
    __shared__ float lds[12352];
    int egb   = blockIdx.x * 64;
    int chunk = blockIdx.y;
    int j0 = chunk * CK;
    int jc = (ND - j0 < CK) ? (ND - j0) : CK;
    const float* Asrc = cfT + (size_t)j0 * 64;
    float* Pt = Op + ((size_t)chunk * 16 + blockIdx.x) * 4096;
    gemm_tile(Asrc, W, ND, egb, j0, jc, Pt, lds);
}

// ---------------- K6: reduce Op chunks + bias -> out ------------------------
__global__ __launch_bounds__(256) void k_fin(
    const float* __restrict__ Op, const float* __restrict__ outb,
    float* __restrict__ out)
{
    int e = blockIdx.x * 256 + threadIdx.x;
    int b = blockIdx.y;
    if (e >= ND) return;
    float s = outb[e];
    size_t cell = ((size_t)(e >> 6)) * 4096 + (b << 6) + (e & 63);
    for (int c = 0; c < NCH_OUT; ++c)
        s += Op[(size_t)c * 16 * 4096 + cell];
    out[(size_t)b * ND + e] = s;
}

extern "C" void kernel_launch(void* const* d_in, const int* in_sizes, int n_in,
                              void* d_out, int out_size, void* d_ws, size_t ws_size,
                              hipStream_t stream)
{
    const float* x    = (const float*)d_in[0];
    const float* g    = (const float*)d_in[1];
    const float* be   = (const float*)d_in[2];
    const float* mu   = (const float*)d_in[3];
    const float* va   = (const float*)d_in[4];
    const float* cwq  = (const float*)d_in[5];
    const float* cbq  = (const float*)d_in[6];
    const float* lwq  = (const float*)d_in[7];
    const float* lbq  = (const float*)d_in[8];
    const float* cwk  = (const float*)d_in[9];
    const float* cbk  = (const float*)d_in[10];
    const float* lwk  = (const float*)d_in[11];
    const float* lbk  = (const float*)d_in[12];
    const float* cwv  = (const float*)d_in[13];
    const float* cbv  = (const float*)d_in[14];
    const float* lwv  = (const float*)d_in[15];
    const float* lbv  = (const float*)d_in[16];
    const float* ipw  = (const float*)d_in[17];
    const float* ipb  = (const float*)d_in[18];
    const float* opw  = (const float*)d_in[19];
    const float* opb  = (const float*)d_in[20];
    const float* W    = (const float*)d_in[21];
    const float* outb = (const float*)d_in[22];

    float* ws    = (float*)d_ws;
    float* convT = ws + OFF_CONVT;
    float* Pp    = ws + OFF_PP;
    float* q     = ws + OFF_Q;
    float* kv    = ws + OFF_KV;
    float* cfT   = ws + OFF_CF;
    float* Op    = ws + OFF_OP;
    float* out   = (float*)d_out;

    k_bnconv<<<dim3(4, 64), 256, 0, stream>>>(x, g, be, mu, va,
                                              cwq, cbq, cwk, cbk, cwv, cbv, convT);
    k_lin  <<<dim3(16, 3, NCH_LIN), 256, 0, stream>>>(convT, lwq, lwk, lwv, Pp);
    k_act  <<<dim3(4, 64), 256, 0, stream>>>(Pp, lbq, lbk, lbv, ipw, ipb, q, kv);
    k_attn <<<dim3(16, 64), 256, 0, stream>>>(q, kv, opw, opb, cfT);
    k_out  <<<dim3(16, NCH_OUT), 256, 0, stream>>>(cfT, W, Op);
    k_fin  <<<dim3(4, 64), 256, 0, stream>>>(Op, outb, out);
}